// Round 1
// baseline (221.048 us; speedup 1.0000x reference)
//
#include <hip/hip_runtime.h>
#include <hip/hip_bf16.h>
#include <stdint.h>

// ---------------------------------------------------------------------------
// CustomConvLayer: out[b,o,h,w] = sum_{c,dh,dw} xpad[b,c,h+dh,w+dw] * W[o,c,dh*3+dw]
// Implicit-im2col GEMM, bf16 MFMA 16x16x32. M=B*H*W, N=128, K=576.
//
// R4 (this round): two-row blocks. Each block owns output rows (h0,h0+1) of one
// image: 4-row xpad slab (66.5 KB LDS, rows h0..h0+3), 512 thr / 8 waves, each
// wave a 64x64 tile (same fragment math as R3). Staging is issued up-front in
// row-major wave-uniform groups and consumed via counted vmcnt waits:
//   issue A(rows0-1) B(row2) C(row3) -> vmcnt(4)+bar -> dh=0 ->
//   vmcnt(2)+bar -> dh=1 -> vmcnt(0)+bar -> dh=2
// so rows 2-3 load UNDER the dh=0 MFMAs instead of a full-drain __syncthreads.
// Block 32 is duplicate-staged by all 8 waves so per-wave issue counts are
// uniform (5+2+2) and the vmcnt values are wave-invariant. zero_border is
// folded into xform_x. B is prepacked in MFMA-fragment order (BtF, 147 KB,
// L2-resident). All fragment arrays remain plain constant-indexed locals (R3).
// ---------------------------------------------------------------------------

typedef __bf16 bf16x8 __attribute__((ext_vector_type(8)));
typedef float  f32x4  __attribute__((ext_vector_type(4)));

#define GLD_TO_LDS16(g, l)                                                        \
  __builtin_amdgcn_global_load_lds((const __attribute__((address_space(1))) void*)(g), \
                                   (__attribute__((address_space(3))) void*)(l), 16, 0, 0)

// ---------------- x NCHW fp32 -> padded NHWC bf16 (+ fused border zeroing) ---
__global__ __launch_bounds__(256) void xform_x(const float* __restrict__ x,
                                               __bf16* __restrict__ xpad) {
  __shared__ float tile[64][129];  // +1 pad: write phase reads column-wise
  const int tid = threadIdx.x;
  const int b = blockIdx.x >> 7;
  const int h = blockIdx.x & 127;

  // ---- border zeroing (independent stores, replaces the zero_border kernel)
  const bf16x8 z8 = {};
  __bf16* prow = xpad + (size_t)(b * 130 + h + 1) * 8320;  // row hp=h+1
  if (tid < 8)        *(bf16x8*)(prow + tid * 8) = z8;               // wp=0
  else if (tid < 16)  *(bf16x8*)(prow + 8256 + (tid - 8) * 8) = z8;  // wp=129
  if (h == 0) {
    bf16x8* r0 = (bf16x8*)(xpad + (size_t)(b * 130) * 8320);         // row hp=0
    for (int i = tid; i < 1040; i += 256) r0[i] = z8;
  } else if (h == 127) {
    bf16x8* r129 = (bf16x8*)(xpad + (size_t)(b * 130 + 129) * 8320); // row hp=129
    for (int i = tid; i < 1040; i += 256) r129[i] = z8;
  }

  const float* src = x + (((size_t)b * 64) * 128 + h) * 128;  // + c*128*128 + w
  for (int i = tid; i < 2048; i += 256) {            // 2048 float4 reads
    const int c = i >> 5, w4 = i & 31;
    f32x4 v = *(const f32x4*)(src + (size_t)c * 16384 + w4 * 4);
    tile[c][w4 * 4 + 0] = v[0];
    tile[c][w4 * 4 + 1] = v[1];
    tile[c][w4 * 4 + 2] = v[2];
    tile[c][w4 * 4 + 3] = v[3];
  }
  __syncthreads();
  __bf16* dst = xpad + ((size_t)(b * 130 + h + 1) * 130 + 1) * 64;
  for (int i = tid; i < 1024; i += 256) {            // 1024 bf16x8 stores
    const int w = i >> 3, cg = i & 7;
    bf16x8 o;
#pragma unroll
    for (int r = 0; r < 8; ++r) o[r] = (__bf16)tile[cg * 8 + r][w];
    *(bf16x8*)(dst + (size_t)w * 64 + cg * 8) = o;
  }
}

// ---------------- weights -> fragment-order BtF[s][quad][n] 16B chunks -------
// chunk(s,quad,n)[r] = W[n][c][tap] with k = s*32+quad*8+r, tap=k>>6, c=k&63
__global__ __launch_bounds__(256) void xform_w(const float* __restrict__ wgt,
                                               __bf16* __restrict__ BtF) {
  const int t = blockIdx.x * 256 + threadIdx.x;  // chunk id
  if (t >= 9216) return;
  const int s = t >> 9, rem = t & 511, quad = rem >> 7, n = rem & 127;
  bf16x8 o;
#pragma unroll
  for (int r = 0; r < 8; ++r) {
    const int k = s * 32 + quad * 8 + r;
    const int tap = k >> 6, c = k & 63;
    o[r] = (__bf16)wgt[(n * 64 + c) * 9 + tap];
  }
  *(bf16x8*)(BtF + (size_t)t * 8) = o;
}

// ---------------- main GEMM: block=(b,h0 pair), 4-row slab, pipelined staging
__global__ __launch_bounds__(512, 4) void conv_mfma(const __bf16* __restrict__ xpad,
                                                    const __bf16* __restrict__ BtF,
                                                    float* __restrict__ out) {
  __shared__ alignas(16) __bf16 Aslab[4160 * 8];  // 66,560 B: 4 rows x 130 w x 64 c
  const int tid  = threadIdx.x;
  const int lane = tid & 63;
  const int wave = tid >> 6;          // 0..7
  const int quad = lane >> 4;
  const int l16  = lane & 15;
  // XCD-aware swizzle: 1024 blocks = 8 XCD x 128; contiguous (b,h0) per XCD
  const int rank = (blockIdx.x & 7) * 128 + (blockIdx.x >> 3);
  const int b  = rank >> 6;
  const int h0 = (rank & 63) << 1;    // output row pair (h0, h0+1)
  const int wn = wave & 1;            // N half
  const int wm = wave >> 1;           // 0..3: (row r, w-half)
  const int r  = wm >> 1;             // output row within pair
  const int wq = (wm & 1) << 6;       // w-half base

  // ---- stage 4-row slab: 4160 16B chunks, XOR swizzle folded into source.
  // LDS chunk l holds source chunk (l&~7) | ((l&7) ^ ((l>>3)&7)).
  // Issue order (per wave, uniform counts): A = rows0-1 (5 blks, blk32 dup'd
  // by all waves), B = row2 (2), C = row3 (2) -> counted vmcnt works.
  const __bf16* slab = xpad + (size_t)(b * 130 + h0) * 8320;
#define STAGE_BLK(BLK) do {                                               \
    const int l_   = ((BLK) << 6) + lane;                                 \
    const int v_   = l_ >> 3;                                             \
    const int cqs_ = (l_ & 7) ^ (v_ & 7);                                 \
    GLD_TO_LDS16(slab + v_ * 64 + cqs_ * 8, (char*)Aslab + ((BLK) << 10)); \
  } while (0)

#pragma unroll
  for (int k = 0; k < 4; ++k) STAGE_BLK(wave + (k << 3));  // blocks 0..31
  STAGE_BLK(32);                                           // slots 2048..2111 (8x dup, benign)
  __builtin_amdgcn_sched_barrier(0);
  STAGE_BLK(33 + wave * 2);                                // blocks 33..48: row 2
  STAGE_BLK(34 + wave * 2);
  __builtin_amdgcn_sched_barrier(0);
  STAGE_BLK(49 + wave * 2);                                // blocks 49..64: row 3
  STAGE_BLK(50 + wave * 2);
  __builtin_amdgcn_sched_barrier(0);

  f32x4 acc[4][4] = {};

  // one K-phase per dh: 3 dw x 2 half = 6 s-steps, 16 MFMA each
#define PHASE(DH)                                                              \
  _Pragma("unroll")                                                            \
  for (int dw = 0; dw < 3; ++dw) {                                             \
    _Pragma("unroll")                                                          \
    for (int half = 0; half < 2; ++half) {                                     \
      const int s_  = ((DH) * 3 + dw) * 2 + half;                              \
      const int cq_ = (half << 2) + quad;                                      \
      bf16x8 aF[4], bF[4]; /* plain locals, constant-indexed (SROA) */         \
      _Pragma("unroll")                                                        \
      for (int i = 0; i < 4; ++i) {                                            \
        const int v_    = ((DH) + r) * 130 + wq + (i << 4) + l16 + dw;         \
        const int slot_ = (v_ << 3) + (cq_ ^ (v_ & 7));                        \
        aF[i] = *(const bf16x8*)(Aslab + (size_t)slot_ * 8);                   \
        bF[i] = *(const bf16x8*)(BtF +                                         \
                 ((size_t)((s_ * 4 + quad) * 128 + (wn << 6) + (i << 4) + l16) << 3)); \
      }                                                                        \
      _Pragma("unroll")                                                        \
      for (int i = 0; i < 4; ++i)                                              \
        _Pragma("unroll")                                                      \
        for (int j = 0; j < 4; ++j)                                            \
          acc[i][j] = __builtin_amdgcn_mfma_f32_16x16x32_bf16(aF[i], bF[j],    \
                                                              acc[i][j], 0, 0, 0); \
    }                                                                          \
  }

  // dh=0 needs rows 0-1 (chunk slots < 2112): wait A (4 outstanding = B+C)
  asm volatile("s_waitcnt vmcnt(4)" ::: "memory");
  __builtin_amdgcn_s_barrier();
  PHASE(0)
  // dh=1 adds row 2 (slots < 3136): wait A+B (2 outstanding = C)
  asm volatile("s_waitcnt vmcnt(2)" ::: "memory");
  __builtin_amdgcn_s_barrier();
  PHASE(1)
  // dh=2 adds row 3: drain
  asm volatile("s_waitcnt vmcnt(0)" ::: "memory");
  __builtin_amdgcn_s_barrier();
  PHASE(2)

  // epilogue: D col = lane&15 = n, row = quad*4+reg = w
#pragma unroll
  for (int j = 0; j < 4; ++j) {
    const int n = (wn << 6) + (j << 4) + l16;
    float* orow = out + (((size_t)(b * 128 + n) * 128 + (h0 + r)) << 7);
#pragma unroll
    for (int i = 0; i < 4; ++i) {
      const int m0 = wq + (i << 4) + (quad << 2);
      *(f32x4*)(orow + m0) = acc[i][j];  // quads 0..3 tile one 64B line per n
    }
  }
}

// ---------------- fallback (if workspace too small): direct fp32 conv -------
__global__ void conv_naive(const float* __restrict__ x, const float* __restrict__ wgt,
                           float* __restrict__ out, int total) {
  int idx = blockIdx.x * 256 + threadIdx.x;
  if (idx >= total) return;
  const int w = idx & 127;
  const int h = (idx >> 7) & 127;
  const int o = (idx >> 14) & 127;
  const int b = idx >> 21;
  float s = 0.f;
  for (int c = 0; c < 64; ++c) {
    const float* xc = x + ((size_t)(b * 64 + c) * 128) * 128;
    const float* wc = wgt + (o * 64 + c) * 9;
    for (int dh = 0; dh < 3; ++dh) {
      const int hh = h + dh - 1;
      if (hh < 0 || hh >= 128) continue;
      for (int dw = 0; dw < 3; ++dw) {
        const int ww = w + dw - 1;
        if (ww < 0 || ww >= 128) continue;
        s += xc[hh * 128 + ww] * wc[dh * 3 + dw];
      }
    }
  }
  out[idx] = s;
}

extern "C" void kernel_launch(void* const* d_in, const int* in_sizes, int n_in,
                              void* d_out, int out_size, void* d_ws, size_t ws_size,
                              hipStream_t stream) {
  const float* x   = (const float*)d_in[0];
  const float* wgt = (const float*)d_in[1];
  float* out = (float*)d_out;

  const size_t BTF_BYTES  = 9216ull * 16;                             // 147456
  const size_t XPAD_BYTES = 16ull * 130 * 130 * 64 * sizeof(__bf16);  // 34.6 MB

  if (ws_size < BTF_BYTES + XPAD_BYTES) {
    const int total = 16 * 128 * 128 * 128;
    conv_naive<<<(total + 255) / 256, 256, 0, stream>>>(x, wgt, out, total);
    return;
  }

  __bf16* BtF  = (__bf16*)d_ws;
  __bf16* xpad = (__bf16*)((char*)d_ws + BTF_BYTES);

  xform_w<<<36, 256, 0, stream>>>(wgt, BtF);
  xform_x<<<16 * 128, 256, 0, stream>>>(x, xpad);  // border zeroing fused
  conv_mfma<<<1024, 512, 0, stream>>>(xpad, BtF, out);
}